// Round 11
// baseline (346.713 us; speedup 1.0000x reference)
//
#include <hip/hip_runtime.h>

#define IN_DIM 128
#define HID    64
#define NCHUNK 128        // coarse pass chunks
#define BWSH   8          // bucket width = 256 nodes
#define BW     (1 << BWSH)

typedef __attribute__((ext_vector_type(4))) _Float16 f16x4;
typedef __attribute__((ext_vector_type(8))) _Float16 f16x8;
typedef __attribute__((ext_vector_type(4))) float    f32x4;

// ==================== build pass A: coarse bucket count (+ weight prep) ====================
__global__ __launch_bounds__(256) void k_bcount(const int* __restrict__ dst,
                                                int* __restrict__ counts,
                                                const float* __restrict__ W1,
                                                const float* __restrict__ W2,
                                                _Float16* __restrict__ W1T,
                                                _Float16* __restrict__ W2T,
                                                int e, int nbk, int ech) {
    int c = blockIdx.x, tid = threadIdx.x;
    if (c >= NCHUNK) {
        int t = (c - NCHUNK) * 256 + tid;   // stride 512 across 2 blocks
        for (int i = t; i < IN_DIM * HID; i += 512) {
            int k = i >> 6, cc = i & 63;
            W1T[cc * IN_DIM + k] = (_Float16)W1[i];
        }
        for (int i = t; i < HID * HID; i += 512) {
            int k = i >> 6, cc = i & 63;
            W2T[cc * HID + k] = (_Float16)W2[i];
        }
        return;
    }
    __shared__ int cnt[512];
    cnt[tid] = 0; cnt[tid + 256] = 0;
    __syncthreads();
    int i0 = c * ech, i1 = min(e, i0 + ech);
    for (int i = i0 + tid; i < i1; i += 256)
        atomicAdd(&cnt[dst[i] >> BWSH], 1);
    __syncthreads();
    for (int b = tid; b < nbk; b += 256) counts[c * nbk + b] = cnt[b];
}

// ==================== build pass B: scan (counts -> starts), single block ====================
__global__ __launch_bounds__(512) void k_bscan(int* __restrict__ counts,
                                               int* __restrict__ bstart,
                                               int* __restrict__ offsets,
                                               int n, int e, int nbk) {
    __shared__ int s[512];
    int b = threadIdx.x;
    int run = 0;
    if (b < nbk) {
        for (int c = 0; c < NCHUNK; ++c) {
            int t = counts[c * nbk + b];
            counts[c * nbk + b] = run;          // chunk-local exclusive within bucket
            run += t;
        }
    }
    s[b] = run;
    __syncthreads();
    for (int off = 1; off < 512; off <<= 1) {
        int t = (b >= off) ? s[b - off] : 0;
        __syncthreads();
        s[b] += t;
        __syncthreads();
    }
    int excl = s[b] - run;                      // exclusive bucket start
    if (b < nbk) {
        bstart[b] = excl;
        for (int c = 0; c < NCHUNK; ++c) counts[c * nbk + b] += excl;
    }
    if (b == 0) { bstart[nbk] = e; offsets[n] = e; }
}

// ==================== build pass C: bucket-partition edges (LDS cursors) ====================
// packs {src | localdst<<24, weight-bits} -> no separate tag array
__global__ __launch_bounds__(256) void k_bscatter(const int* __restrict__ src,
                                                  const int* __restrict__ dst,
                                                  const float* __restrict__ ew,
                                                  const int* __restrict__ starts,
                                                  int2* __restrict__ tmpe,
                                                  int e, int nbk, int ech) {
    __shared__ int cur[512];
    int c = blockIdx.x, tid = threadIdx.x;
    for (int b = tid; b < nbk; b += 256) cur[b] = starts[c * nbk + b];
    __syncthreads();
    int i0 = c * ech, i1 = min(e, i0 + ech);
    for (int i = i0 + tid; i < i1; i += 256) {
        int d = dst[i];
        int b = d >> BWSH;
        int pos = atomicAdd(&cur[b], 1);
        tmpe[pos] = make_int2(src[i] | ((d & (BW - 1)) << 24), __float_as_int(ew[i]));
    }
}

// ==================== build pass D: per-bucket fine sort + offsets + dinv ====================
__global__ __launch_bounds__(256) void k_bfine(const int* __restrict__ bstart,
                                               const int2* __restrict__ tmpe,
                                               int2* __restrict__ sedge,
                                               int* __restrict__ offsets,
                                               float* __restrict__ dinv, int n) {
    __shared__ int   cnt[256];
    __shared__ float wsum[256];
    __shared__ int   lsc[256];
    __shared__ int   cur[256];
    int b = blockIdx.x, tid = threadIdx.x;
    int bs = bstart[b], be = bstart[b + 1];
    cnt[tid] = 0; wsum[tid] = 0.0f;
    __syncthreads();
    for (int j = bs + tid; j < be; j += 256) {
        int2 ed = tmpe[j];
        int ld = (unsigned)ed.x >> 24;
        atomicAdd(&cnt[ld], 1);
        atomicAdd(&wsum[ld], __int_as_float(ed.y));
    }
    __syncthreads();
    int v = cnt[tid];
    lsc[tid] = v;
    __syncthreads();
    for (int off = 1; off < 256; off <<= 1) {
        int t = (tid >= off) ? lsc[tid - off] : 0;
        __syncthreads();
        lsc[tid] += t;
        __syncthreads();
    }
    int excl = lsc[tid] - v;
    int node = b * BW + tid;
    if (node < n) {
        offsets[node] = bs + excl;
        dinv[node] = rsqrtf(1.0f + wsum[tid]);   // self-loop weight 1
    }
    cur[tid] = excl;
    __syncthreads();
    for (int j = bs + tid; j < be; j += 256) {
        int2 ed = tmpe[j];
        int ld = (unsigned)ed.x >> 24;
        int pos = bs + atomicAdd(&cur[ld], 1);
        sedge[pos] = make_int2(ed.x & 0xFFFFFF, ed.y);
    }
}

// ==================== GEMMs (MFMA f16, dinv-scaled epilogue) ====================

__global__ __launch_bounds__(256) void k_gemm1(const float* __restrict__ x,
                                               const _Float16* __restrict__ W1T,
                                               const float* __restrict__ dinv,
                                               _Float16* __restrict__ h0, int n) {
    __shared__ _Float16 sX[4][16 * IN_DIM];
    int tid  = threadIdx.x;
    int wave = tid >> 6, lane = tid & 63;
    int row0 = blockIdx.x * 64 + wave * 16;
    int col  = lane & 15, kg = lane >> 4;

    f16x8 bfrag[4][4];
    #pragma unroll
    for (int ks = 0; ks < 4; ++ks)
        #pragma unroll
        for (int ct = 0; ct < 4; ++ct)
            bfrag[ks][ct] = *(const f16x8*)(W1T + (ct * 16 + col) * IN_DIM + ks * 32 + kg * 8);

    _Float16* myX = sX[wave];
    #pragma unroll
    for (int it = 0; it < 8; ++it) {
        int idx = it * 64 + lane;
        int r = idx >> 5, c4 = idx & 31;
        int grow = row0 + r;
        float4 v = make_float4(0.f, 0.f, 0.f, 0.f);
        if (grow < n) v = ((const float4*)x)[(size_t)grow * 32 + c4];
        f16x4 h; h.x = (_Float16)v.x; h.y = (_Float16)v.y; h.z = (_Float16)v.z; h.w = (_Float16)v.w;
        int off = (r * 256 + c4 * 8) ^ ((r & 7) << 4);
        *(f16x4*)((char*)myX + off) = h;
    }
    __syncthreads();

    f32x4 acc[4];
    #pragma unroll
    for (int ct = 0; ct < 4; ++ct) acc[ct] = (f32x4){0.f, 0.f, 0.f, 0.f};

    int arow = lane & 15;
    #pragma unroll
    for (int ks = 0; ks < 4; ++ks) {
        int off = (arow * 256 + kg * 16 + ks * 64) ^ ((arow & 7) << 4);
        f16x8 af = *(const f16x8*)((const char*)myX + off);
        #pragma unroll
        for (int ct = 0; ct < 4; ++ct)
            acc[ct] = __builtin_amdgcn_mfma_f32_16x16x32_f16(af, bfrag[ks][ct], acc[ct], 0, 0, 0);
    }

    int crow0 = row0 + kg * 4;
    #pragma unroll
    for (int r = 0; r < 4; ++r) {
        int gr = crow0 + r;
        if (gr < n) {
            float dv = dinv[gr];
            #pragma unroll
            for (int ct = 0; ct < 4; ++ct)
                h0[(size_t)gr * HID + ct * 16 + col] = (_Float16)(acc[ct][r] * dv);
        }
    }
}

__global__ __launch_bounds__(256) void k_gemm2(const _Float16* __restrict__ h1,
                                               const _Float16* __restrict__ W2T,
                                               const float* __restrict__ dinv,
                                               _Float16* __restrict__ h2, int n) {
    __shared__ _Float16 sX[4][16 * HID];
    int tid  = threadIdx.x;
    int wave = tid >> 6, lane = tid & 63;
    int row0 = blockIdx.x * 64 + wave * 16;
    int col  = lane & 15, kg = lane >> 4;

    f16x8 bfrag[2][4];
    #pragma unroll
    for (int ks = 0; ks < 2; ++ks)
        #pragma unroll
        for (int ct = 0; ct < 4; ++ct)
            bfrag[ks][ct] = *(const f16x8*)(W2T + (ct * 16 + col) * HID + ks * 32 + kg * 8);

    _Float16* myX = sX[wave];
    #pragma unroll
    for (int it = 0; it < 4; ++it) {
        int idx = it * 64 + lane;
        int r = idx >> 4, c4 = idx & 15;
        int grow = row0 + r;
        f16x4 h = (f16x4){0, 0, 0, 0};
        if (grow < n) h = ((const f16x4*)h1)[(size_t)grow * 16 + c4];
        int off = (r * 128 + c4 * 8) ^ ((r & 7) << 4);
        *(f16x4*)((char*)myX + off) = h;
    }
    __syncthreads();

    f32x4 acc[4];
    #pragma unroll
    for (int ct = 0; ct < 4; ++ct) acc[ct] = (f32x4){0.f, 0.f, 0.f, 0.f};

    int arow = lane & 15;
    #pragma unroll
    for (int ks = 0; ks < 2; ++ks) {
        int off = (arow * 128 + kg * 16 + ks * 64) ^ ((arow & 7) << 4);
        f16x8 af = *(const f16x8*)((const char*)myX + off);
        #pragma unroll
        for (int ct = 0; ct < 4; ++ct)
            acc[ct] = __builtin_amdgcn_mfma_f32_16x16x32_f16(af, bfrag[ks][ct], acc[ct], 0, 0, 0);
    }

    int crow0 = row0 + kg * 4;
    #pragma unroll
    for (int r = 0; r < 4; ++r) {
        int gr = crow0 + r;
        if (gr < n) {
            float dv = dinv[gr];
            #pragma unroll
            for (int ct = 0; ct < 4; ++ct)
                h2[(size_t)gr * HID + ct * 16 + col] = (_Float16)(acc[ct][r] * dv);
        }
    }
}

// ==================== CSR propagate: 8 nodes/wave, 8-deep batches, persistent grid ====================

__global__ __launch_bounds__(256, 8) void k_prop1(const int* __restrict__ offR,
                                                  const int2* __restrict__ sedge,
                                                  const _Float16* __restrict__ hin,
                                                  const float* __restrict__ dinv,
                                                  const float* __restrict__ b1,
                                                  _Float16* __restrict__ hout, int n) {
    int wid0 = (blockIdx.x * blockDim.x + threadIdx.x) >> 6;
    int lane = threadIdx.x & 63;
    int g    = lane >> 3;
    int gl   = lane & 7;
    int nOct = (n + 7) >> 3;
    int nWav = (gridDim.x * blockDim.x) >> 6;

    float4 bbA = ((const float4*)b1)[gl * 2];
    float4 bbB = ((const float4*)b1)[gl * 2 + 1];

    for (int oct = wid0; oct < nOct; oct += nWav) {
        int node = oct * 8 + g;
        bool valid = node < n;
        int nd = valid ? node : 0;

        int start = offR[nd];
        int end   = valid ? offR[nd + 1] : start;
        float di  = dinv[nd];

        f16x8 sv = *(const f16x8*)(hin + (size_t)nd * HID + gl * 8);
        float a[8];
        #pragma unroll
        for (int t = 0; t < 8; ++t) a[t] = (float)sv[t];

        int j = start;
        for (; j + 8 <= end; j += 8) {
            int2 ed[8]; f16x8 v[8]; float w[8];
            #pragma unroll
            for (int k = 0; k < 8; ++k) ed[k] = sedge[j + k];
            #pragma unroll
            for (int k = 0; k < 8; ++k) v[k] = *(const f16x8*)(hin + (size_t)ed[k].x * HID + gl * 8);
            #pragma unroll
            for (int k = 0; k < 8; ++k) w[k] = __int_as_float(ed[k].y);
            #pragma unroll
            for (int k = 0; k < 8; ++k)
                #pragma unroll
                for (int t = 0; t < 8; ++t) a[t] = fmaf((float)v[k][t], w[k], a[t]);
        }
        if (j < end) {
            #pragma unroll
            for (int k = 0; k < 8; ++k) {
                int idx = j + k;
                int cl  = idx < end ? idx : j;
                int2 ed = sedge[cl];
                float w = idx < end ? __int_as_float(ed.y) : 0.0f;
                f16x8 v = *(const f16x8*)(hin + (size_t)ed.x * HID + gl * 8);
                #pragma unroll
                for (int t = 0; t < 8; ++t) a[t] = fmaf((float)v[t], w, a[t]);
            }
        }

        if (valid) {
            f16x8 o;
            o[0] = (_Float16)fmaxf(fmaf(a[0], di, bbA.x), 0.0f);
            o[1] = (_Float16)fmaxf(fmaf(a[1], di, bbA.y), 0.0f);
            o[2] = (_Float16)fmaxf(fmaf(a[2], di, bbA.z), 0.0f);
            o[3] = (_Float16)fmaxf(fmaf(a[3], di, bbA.w), 0.0f);
            o[4] = (_Float16)fmaxf(fmaf(a[4], di, bbB.x), 0.0f);
            o[5] = (_Float16)fmaxf(fmaf(a[5], di, bbB.y), 0.0f);
            o[6] = (_Float16)fmaxf(fmaf(a[6], di, bbB.z), 0.0f);
            o[7] = (_Float16)fmaxf(fmaf(a[7], di, bbB.w), 0.0f);
            *(f16x8*)(hout + (size_t)node * HID + gl * 8) = o;
        }
    }
}

__global__ __launch_bounds__(256, 8) void k_prop2_final(const int* __restrict__ offR,
                                                        const int2* __restrict__ sedge,
                                                        const _Float16* __restrict__ hin,
                                                        const float* __restrict__ dinv,
                                                        const float* __restrict__ b2,
                                                        const float* __restrict__ Wl,
                                                        const float* __restrict__ bl,
                                                        float* __restrict__ out, int n) {
    int wid0 = (blockIdx.x * blockDim.x + threadIdx.x) >> 6;
    int lane = threadIdx.x & 63;
    int g    = lane >> 3;
    int gl   = lane & 7;
    int nOct = (n + 7) >> 3;
    int nWav = (gridDim.x * blockDim.x) >> 6;

    float4 bbA = ((const float4*)b2)[gl * 2];
    float4 bbB = ((const float4*)b2)[gl * 2 + 1];
    float4 wlA = ((const float4*)Wl)[gl * 2];
    float4 wlB = ((const float4*)Wl)[gl * 2 + 1];
    float bb[8] = {bbA.x, bbA.y, bbA.z, bbA.w, bbB.x, bbB.y, bbB.z, bbB.w};
    float wl[8] = {wlA.x, wlA.y, wlA.z, wlA.w, wlB.x, wlB.y, wlB.z, wlB.w};
    float blv = bl[0];

    for (int oct = wid0; oct < nOct; oct += nWav) {
        int node = oct * 8 + g;
        bool valid = node < n;
        int nd = valid ? node : 0;

        int start = offR[nd];
        int end   = valid ? offR[nd + 1] : start;
        float di  = dinv[nd];

        f16x8 sv = *(const f16x8*)(hin + (size_t)nd * HID + gl * 8);
        float a[8];
        #pragma unroll
        for (int t = 0; t < 8; ++t) a[t] = (float)sv[t];

        int j = start;
        for (; j + 8 <= end; j += 8) {
            int2 ed[8]; f16x8 v[8]; float w[8];
            #pragma unroll
            for (int k = 0; k < 8; ++k) ed[k] = sedge[j + k];
            #pragma unroll
            for (int k = 0; k < 8; ++k) v[k] = *(const f16x8*)(hin + (size_t)ed[k].x * HID + gl * 8);
            #pragma unroll
            for (int k = 0; k < 8; ++k) w[k] = __int_as_float(ed[k].y);
            #pragma unroll
            for (int k = 0; k < 8; ++k)
                #pragma unroll
                for (int t = 0; t < 8; ++t) a[t] = fmaf((float)v[k][t], w[k], a[t]);
        }
        if (j < end) {
            #pragma unroll
            for (int k = 0; k < 8; ++k) {
                int idx = j + k;
                int cl  = idx < end ? idx : j;
                int2 ed = sedge[cl];
                float w = idx < end ? __int_as_float(ed.y) : 0.0f;
                f16x8 v = *(const f16x8*)(hin + (size_t)ed.x * HID + gl * 8);
                #pragma unroll
                for (int t = 0; t < 8; ++t) a[t] = fmaf((float)v[t], w, a[t]);
            }
        }

        float v = 0.0f;
        #pragma unroll
        for (int t = 0; t < 8; ++t)
            v += fmaxf(fmaf(a[t], di, bb[t]), 0.0f) * wl[t];
        #pragma unroll
        for (int off = 1; off < 8; off <<= 1)
            v += __shfl_xor(v, off);
        if (valid && gl == 0) out[node] = v + blv;
    }
}

// ==================== launch ====================

static inline char* align16(char* p) {
    return (char*)(((uintptr_t)p + 15) & ~(uintptr_t)15);
}

extern "C" void kernel_launch(void* const* d_in, const int* in_sizes, int n_in,
                              void* d_out, int out_size, void* d_ws, size_t ws_size,
                              hipStream_t stream) {
    const float* x   = (const float*)d_in[0];
    const int*   ei  = (const int*)d_in[1];
    const float* ew  = (const float*)d_in[2];
    const float* W1  = (const float*)d_in[3];
    const float* b1  = (const float*)d_in[4];
    const float* W2  = (const float*)d_in[5];
    const float* b2  = (const float*)d_in[6];
    const float* Wl  = (const float*)d_in[7];
    const float* bl  = (const float*)d_in[8];

    const int n = in_sizes[0] / IN_DIM;   // 100000
    const int e = in_sizes[2];            // 1000000
    const int* src = ei;
    const int* dst = ei + e;

    float* out = (float*)d_out;
    const int B256 = 256;
    const int nbk = (n + BW - 1) >> BWSH;          // 391 buckets (<= 512 required)
    const int ech = (e + NCHUNK - 1) / NCHUNK;     // edges per chunk

    // workspace layout (16B-aligned slices)
    char* p = (char*)d_ws;
    int2*           sedge   = (int2*)p;            p += (size_t)e * 8;
    int2*           tmpe    = (int2*)p;            p += (size_t)e * 8;
    p = align16(p);
    float*          dinv    = (float*)p;           p += (size_t)n * 4;
    int*            offsets = (int*)p;             p += ((size_t)n + 1) * 4;
    p = align16(p);
    int*            counts  = (int*)p;             p += (size_t)NCHUNK * nbk * 4;
    int*            bstart  = (int*)p;             p += ((size_t)nbk + 1) * 4;
    p = align16(p);
    _Float16*       W1T     = (_Float16*)p;        p += IN_DIM * HID * 2;
    _Float16*       W2T     = (_Float16*)p;        p += HID * HID * 2;
    p = align16(p);
    _Float16*       A       = (_Float16*)p;        p += (size_t)n * HID * 2;
    _Float16*       B       = (_Float16*)p;        p += (size_t)n * HID * 2;

    // build: count -> scan -> bucket-partition -> fine sort (+offsets+dinv)
    k_bcount  <<<NCHUNK + 2, B256, 0, stream>>>(dst, counts, W1, W2, W1T, W2T, e, nbk, ech);
    k_bscan   <<<1, 512, 0, stream>>>(counts, bstart, offsets, n, e, nbk);
    k_bscatter<<<NCHUNK, B256, 0, stream>>>(src, dst, ew, counts, tmpe, e, nbk, ech);
    k_bfine   <<<nbk, B256, 0, stream>>>(bstart, tmpe, sedge, offsets, dinv, n);

    const int gemmBlocks = (n + 63) / 64;
    const int nOct = (n + 7) >> 3;
    const int propBlocks = min((nOct + 3) / 4, 2048);   // persistent-ish grid

    k_gemm1<<<gemmBlocks, B256, 0, stream>>>(x, W1T, dinv, A, n);
    k_prop1<<<propBlocks, B256, 0, stream>>>(offsets, sedge, A, dinv, b1, B, n);

    k_gemm2<<<gemmBlocks, B256, 0, stream>>>(B, W2T, dinv, A, n);
    k_prop2_final<<<propBlocks, B256, 0, stream>>>(offsets, sedge, A, dinv,
                                                   b2, Wl, bl, out, n);
}

// Round 12
// 197.827 us; speedup vs baseline: 1.7526x; 1.7526x over previous
//
#include <hip/hip_runtime.h>

#define IN_DIM 128
#define HID    64
#define NCHUNK 128        // coarse pass chunks
#define BWSH   8          // bucket width = 256 nodes
#define BW     (1 << BWSH)

typedef __attribute__((ext_vector_type(4))) _Float16 f16x4;
typedef __attribute__((ext_vector_type(8))) _Float16 f16x8;
typedef __attribute__((ext_vector_type(4))) float    f32x4;

// ==================== build pass A: coarse bucket count (+ weight prep) ====================
__global__ __launch_bounds__(256) void k_bcount(const int* __restrict__ dst,
                                                int* __restrict__ counts,
                                                const float* __restrict__ W1,
                                                const float* __restrict__ W2,
                                                _Float16* __restrict__ W1T,
                                                _Float16* __restrict__ W2T,
                                                int e, int nbk, int ech) {
    int c = blockIdx.x, tid = threadIdx.x;
    if (c >= NCHUNK) {
        int t = (c - NCHUNK) * 256 + tid;   // stride 512 across 2 blocks
        for (int i = t; i < IN_DIM * HID; i += 512) {
            int k = i >> 6, cc = i & 63;
            W1T[cc * IN_DIM + k] = (_Float16)W1[i];
        }
        for (int i = t; i < HID * HID; i += 512) {
            int k = i >> 6, cc = i & 63;
            W2T[cc * HID + k] = (_Float16)W2[i];
        }
        return;
    }
    __shared__ int cnt[512];
    cnt[tid] = 0; cnt[tid + 256] = 0;
    __syncthreads();
    int i0 = c * ech, i1 = min(e, i0 + ech);
    for (int i = i0 + tid; i < i1; i += 256)
        atomicAdd(&cnt[dst[i] >> BWSH], 1);
    __syncthreads();
    for (int b = tid; b < nbk; b += 256) counts[c * nbk + b] = cnt[b];
}

// ==================== build pass B: scan (counts -> starts), single block ====================
__global__ __launch_bounds__(512) void k_bscan(int* __restrict__ counts,
                                               int* __restrict__ bstart,
                                               int* __restrict__ offsets,
                                               int n, int e, int nbk) {
    __shared__ int s[512];
    int b = threadIdx.x;
    int run = 0;
    if (b < nbk) {
        for (int c = 0; c < NCHUNK; ++c) {
            int t = counts[c * nbk + b];
            counts[c * nbk + b] = run;          // chunk-local exclusive within bucket
            run += t;
        }
    }
    s[b] = run;
    __syncthreads();
    for (int off = 1; off < 512; off <<= 1) {
        int t = (b >= off) ? s[b - off] : 0;
        __syncthreads();
        s[b] += t;
        __syncthreads();
    }
    int excl = s[b] - run;                      // exclusive bucket start
    if (b < nbk) {
        bstart[b] = excl;
        for (int c = 0; c < NCHUNK; ++c) counts[c * nbk + b] += excl;
    }
    if (b == 0) { bstart[nbk] = e; offsets[n] = e; }
}

// ==================== build pass C: bucket-partition edges (LDS cursors) ====================
// packs {src | localdst<<24, weight-bits} -> no separate tag array
__global__ __launch_bounds__(256) void k_bscatter(const int* __restrict__ src,
                                                  const int* __restrict__ dst,
                                                  const float* __restrict__ ew,
                                                  const int* __restrict__ starts,
                                                  int2* __restrict__ tmpe,
                                                  int e, int nbk, int ech) {
    __shared__ int cur[512];
    int c = blockIdx.x, tid = threadIdx.x;
    for (int b = tid; b < nbk; b += 256) cur[b] = starts[c * nbk + b];
    __syncthreads();
    int i0 = c * ech, i1 = min(e, i0 + ech);
    for (int i = i0 + tid; i < i1; i += 256) {
        int d = dst[i];
        int b = d >> BWSH;
        int pos = atomicAdd(&cur[b], 1);
        tmpe[pos] = make_int2(src[i] | ((d & (BW - 1)) << 24), __float_as_int(ew[i]));
    }
}

// ==================== build pass D: per-bucket fine sort + offsets + dinv ====================
__global__ __launch_bounds__(256) void k_bfine(const int* __restrict__ bstart,
                                               const int2* __restrict__ tmpe,
                                               int2* __restrict__ sedge,
                                               int* __restrict__ offsets,
                                               float* __restrict__ dinv, int n) {
    __shared__ int   cnt[256];
    __shared__ float wsum[256];
    __shared__ int   lsc[256];
    __shared__ int   cur[256];
    int b = blockIdx.x, tid = threadIdx.x;
    int bs = bstart[b], be = bstart[b + 1];
    cnt[tid] = 0; wsum[tid] = 0.0f;
    __syncthreads();
    for (int j = bs + tid; j < be; j += 256) {
        int2 ed = tmpe[j];
        int ld = (unsigned)ed.x >> 24;
        atomicAdd(&cnt[ld], 1);
        atomicAdd(&wsum[ld], __int_as_float(ed.y));
    }
    __syncthreads();
    int v = cnt[tid];
    lsc[tid] = v;
    __syncthreads();
    for (int off = 1; off < 256; off <<= 1) {
        int t = (tid >= off) ? lsc[tid - off] : 0;
        __syncthreads();
        lsc[tid] += t;
        __syncthreads();
    }
    int excl = lsc[tid] - v;
    int node = b * BW + tid;
    if (node < n) {
        offsets[node] = bs + excl;
        dinv[node] = rsqrtf(1.0f + wsum[tid]);   // self-loop weight 1
    }
    cur[tid] = excl;
    __syncthreads();
    for (int j = bs + tid; j < be; j += 256) {
        int2 ed = tmpe[j];
        int ld = (unsigned)ed.x >> 24;
        int pos = bs + atomicAdd(&cur[ld], 1);
        sedge[pos] = make_int2(ed.x & 0xFFFFFF, ed.y);
    }
}

// ==================== GEMMs (MFMA f16, dinv-scaled epilogue) ====================

__global__ __launch_bounds__(256) void k_gemm1(const float* __restrict__ x,
                                               const _Float16* __restrict__ W1T,
                                               const float* __restrict__ dinv,
                                               _Float16* __restrict__ h0, int n) {
    __shared__ _Float16 sX[4][16 * IN_DIM];
    int tid  = threadIdx.x;
    int wave = tid >> 6, lane = tid & 63;
    int row0 = blockIdx.x * 64 + wave * 16;
    int col  = lane & 15, kg = lane >> 4;

    f16x8 bfrag[4][4];
    #pragma unroll
    for (int ks = 0; ks < 4; ++ks)
        #pragma unroll
        for (int ct = 0; ct < 4; ++ct)
            bfrag[ks][ct] = *(const f16x8*)(W1T + (ct * 16 + col) * IN_DIM + ks * 32 + kg * 8);

    _Float16* myX = sX[wave];
    #pragma unroll
    for (int it = 0; it < 8; ++it) {
        int idx = it * 64 + lane;
        int r = idx >> 5, c4 = idx & 31;
        int grow = row0 + r;
        float4 v = make_float4(0.f, 0.f, 0.f, 0.f);
        if (grow < n) v = ((const float4*)x)[(size_t)grow * 32 + c4];
        f16x4 h; h.x = (_Float16)v.x; h.y = (_Float16)v.y; h.z = (_Float16)v.z; h.w = (_Float16)v.w;
        int off = (r * 256 + c4 * 8) ^ ((r & 7) << 4);
        *(f16x4*)((char*)myX + off) = h;
    }
    __syncthreads();

    f32x4 acc[4];
    #pragma unroll
    for (int ct = 0; ct < 4; ++ct) acc[ct] = (f32x4){0.f, 0.f, 0.f, 0.f};

    int arow = lane & 15;
    #pragma unroll
    for (int ks = 0; ks < 4; ++ks) {
        int off = (arow * 256 + kg * 16 + ks * 64) ^ ((arow & 7) << 4);
        f16x8 af = *(const f16x8*)((const char*)myX + off);
        #pragma unroll
        for (int ct = 0; ct < 4; ++ct)
            acc[ct] = __builtin_amdgcn_mfma_f32_16x16x32_f16(af, bfrag[ks][ct], acc[ct], 0, 0, 0);
    }

    int crow0 = row0 + kg * 4;
    #pragma unroll
    for (int r = 0; r < 4; ++r) {
        int gr = crow0 + r;
        if (gr < n) {
            float dv = dinv[gr];
            #pragma unroll
            for (int ct = 0; ct < 4; ++ct)
                h0[(size_t)gr * HID + ct * 16 + col] = (_Float16)(acc[ct][r] * dv);
        }
    }
}

__global__ __launch_bounds__(256) void k_gemm2(const _Float16* __restrict__ h1,
                                               const _Float16* __restrict__ W2T,
                                               const float* __restrict__ dinv,
                                               _Float16* __restrict__ h2, int n) {
    __shared__ _Float16 sX[4][16 * HID];
    int tid  = threadIdx.x;
    int wave = tid >> 6, lane = tid & 63;
    int row0 = blockIdx.x * 64 + wave * 16;
    int col  = lane & 15, kg = lane >> 4;

    f16x8 bfrag[2][4];
    #pragma unroll
    for (int ks = 0; ks < 2; ++ks)
        #pragma unroll
        for (int ct = 0; ct < 4; ++ct)
            bfrag[ks][ct] = *(const f16x8*)(W2T + (ct * 16 + col) * HID + ks * 32 + kg * 8);

    _Float16* myX = sX[wave];
    #pragma unroll
    for (int it = 0; it < 4; ++it) {
        int idx = it * 64 + lane;
        int r = idx >> 4, c4 = idx & 15;
        int grow = row0 + r;
        f16x4 h = (f16x4){0, 0, 0, 0};
        if (grow < n) h = ((const f16x4*)h1)[(size_t)grow * 16 + c4];
        int off = (r * 128 + c4 * 8) ^ ((r & 7) << 4);
        *(f16x4*)((char*)myX + off) = h;
    }
    __syncthreads();

    f32x4 acc[4];
    #pragma unroll
    for (int ct = 0; ct < 4; ++ct) acc[ct] = (f32x4){0.f, 0.f, 0.f, 0.f};

    int arow = lane & 15;
    #pragma unroll
    for (int ks = 0; ks < 2; ++ks) {
        int off = (arow * 128 + kg * 16 + ks * 64) ^ ((arow & 7) << 4);
        f16x8 af = *(const f16x8*)((const char*)myX + off);
        #pragma unroll
        for (int ct = 0; ct < 4; ++ct)
            acc[ct] = __builtin_amdgcn_mfma_f32_16x16x32_f16(af, bfrag[ks][ct], acc[ct], 0, 0, 0);
    }

    int crow0 = row0 + kg * 4;
    #pragma unroll
    for (int r = 0; r < 4; ++r) {
        int gr = crow0 + r;
        if (gr < n) {
            float dv = dinv[gr];
            #pragma unroll
            for (int ct = 0; ct < 4; ++ct)
                h2[(size_t)gr * HID + ct * 16 + col] = (_Float16)(acc[ct][r] * dv);
        }
    }
}

// ==================== CSR propagate: 8 nodes/wave, 8-deep gather batches ====================
// (round-10 proven shape: no min-waves clause -> 52 VGPR, no spill)

__global__ __launch_bounds__(256) void k_prop1(const int* __restrict__ offR,
                                               const int2* __restrict__ sedge,
                                               const _Float16* __restrict__ hin,
                                               const float* __restrict__ dinv,
                                               const float* __restrict__ b1,
                                               _Float16* __restrict__ hout, int n) {
    int wave = (blockIdx.x * blockDim.x + threadIdx.x) >> 6;
    int lane = threadIdx.x & 63;
    int g    = lane >> 3;
    int gl   = lane & 7;
    int node = wave * 8 + g;
    bool valid = node < n;
    int nd = valid ? node : 0;

    int start = offR[nd];
    int end   = valid ? offR[nd + 1] : start;

    float di = dinv[nd];
    float4 bbA = ((const float4*)b1)[gl * 2];
    float4 bbB = ((const float4*)b1)[gl * 2 + 1];

    f16x8 sv = *(const f16x8*)(hin + (size_t)nd * HID + gl * 8);
    float a[8];
    #pragma unroll
    for (int t = 0; t < 8; ++t) a[t] = (float)sv[t];

    int j = start;
    for (; j + 8 <= end; j += 8) {
        int2 ed[8]; f16x8 v[8]; float w[8];
        #pragma unroll
        for (int k = 0; k < 8; ++k) ed[k] = sedge[j + k];
        #pragma unroll
        for (int k = 0; k < 8; ++k) v[k] = *(const f16x8*)(hin + (size_t)ed[k].x * HID + gl * 8);
        #pragma unroll
        for (int k = 0; k < 8; ++k) w[k] = __int_as_float(ed[k].y);
        #pragma unroll
        for (int k = 0; k < 8; ++k)
            #pragma unroll
            for (int t = 0; t < 8; ++t) a[t] = fmaf((float)v[k][t], w[k], a[t]);
    }
    if (j < end) {
        #pragma unroll
        for (int k = 0; k < 8; ++k) {
            int idx = j + k;
            int cl  = idx < end ? idx : j;
            int2 ed = sedge[cl];
            float w = idx < end ? __int_as_float(ed.y) : 0.0f;
            f16x8 v = *(const f16x8*)(hin + (size_t)ed.x * HID + gl * 8);
            #pragma unroll
            for (int t = 0; t < 8; ++t) a[t] = fmaf((float)v[t], w, a[t]);
        }
    }

    if (valid) {
        f16x8 o;
        o[0] = (_Float16)fmaxf(fmaf(a[0], di, bbA.x), 0.0f);
        o[1] = (_Float16)fmaxf(fmaf(a[1], di, bbA.y), 0.0f);
        o[2] = (_Float16)fmaxf(fmaf(a[2], di, bbA.z), 0.0f);
        o[3] = (_Float16)fmaxf(fmaf(a[3], di, bbA.w), 0.0f);
        o[4] = (_Float16)fmaxf(fmaf(a[4], di, bbB.x), 0.0f);
        o[5] = (_Float16)fmaxf(fmaf(a[5], di, bbB.y), 0.0f);
        o[6] = (_Float16)fmaxf(fmaf(a[6], di, bbB.z), 0.0f);
        o[7] = (_Float16)fmaxf(fmaf(a[7], di, bbB.w), 0.0f);
        *(f16x8*)(hout + (size_t)node * HID + gl * 8) = o;
    }
}

__global__ __launch_bounds__(256) void k_prop2_final(const int* __restrict__ offR,
                                                     const int2* __restrict__ sedge,
                                                     const _Float16* __restrict__ hin,
                                                     const float* __restrict__ dinv,
                                                     const float* __restrict__ b2,
                                                     const float* __restrict__ Wl,
                                                     const float* __restrict__ bl,
                                                     float* __restrict__ out, int n) {
    int wave = (blockIdx.x * blockDim.x + threadIdx.x) >> 6;
    int lane = threadIdx.x & 63;
    int g    = lane >> 3;
    int gl   = lane & 7;
    int node = wave * 8 + g;
    bool valid = node < n;
    int nd = valid ? node : 0;

    int start = offR[nd];
    int end   = valid ? offR[nd + 1] : start;

    float di = dinv[nd];
    float4 bbA = ((const float4*)b2)[gl * 2];
    float4 bbB = ((const float4*)b2)[gl * 2 + 1];
    float4 wlA = ((const float4*)Wl)[gl * 2];
    float4 wlB = ((const float4*)Wl)[gl * 2 + 1];

    f16x8 sv = *(const f16x8*)(hin + (size_t)nd * HID + gl * 8);
    float a[8];
    #pragma unroll
    for (int t = 0; t < 8; ++t) a[t] = (float)sv[t];

    int j = start;
    for (; j + 8 <= end; j += 8) {
        int2 ed[8]; f16x8 v[8]; float w[8];
        #pragma unroll
        for (int k = 0; k < 8; ++k) ed[k] = sedge[j + k];
        #pragma unroll
        for (int k = 0; k < 8; ++k) v[k] = *(const f16x8*)(hin + (size_t)ed[k].x * HID + gl * 8);
        #pragma unroll
        for (int k = 0; k < 8; ++k) w[k] = __int_as_float(ed[k].y);
        #pragma unroll
        for (int k = 0; k < 8; ++k)
            #pragma unroll
            for (int t = 0; t < 8; ++t) a[t] = fmaf((float)v[k][t], w[k], a[t]);
    }
    if (j < end) {
        #pragma unroll
        for (int k = 0; k < 8; ++k) {
            int idx = j + k;
            int cl  = idx < end ? idx : j;
            int2 ed = sedge[cl];
            float w = idx < end ? __int_as_float(ed.y) : 0.0f;
            f16x8 v = *(const f16x8*)(hin + (size_t)ed.x * HID + gl * 8);
            #pragma unroll
            for (int t = 0; t < 8; ++t) a[t] = fmaf((float)v[t], w, a[t]);
        }
    }

    float bb[8] = {bbA.x, bbA.y, bbA.z, bbA.w, bbB.x, bbB.y, bbB.z, bbB.w};
    float wl[8] = {wlA.x, wlA.y, wlA.z, wlA.w, wlB.x, wlB.y, wlB.z, wlB.w};
    float v = 0.0f;
    #pragma unroll
    for (int t = 0; t < 8; ++t)
        v += fmaxf(fmaf(a[t], di, bb[t]), 0.0f) * wl[t];
    #pragma unroll
    for (int off = 1; off < 8; off <<= 1)
        v += __shfl_xor(v, off);
    if (valid && gl == 0) out[node] = v + bl[0];
}

// ==================== launch ====================

static inline char* align16(char* p) {
    return (char*)(((uintptr_t)p + 15) & ~(uintptr_t)15);
}

extern "C" void kernel_launch(void* const* d_in, const int* in_sizes, int n_in,
                              void* d_out, int out_size, void* d_ws, size_t ws_size,
                              hipStream_t stream) {
    const float* x   = (const float*)d_in[0];
    const int*   ei  = (const int*)d_in[1];
    const float* ew  = (const float*)d_in[2];
    const float* W1  = (const float*)d_in[3];
    const float* b1  = (const float*)d_in[4];
    const float* W2  = (const float*)d_in[5];
    const float* b2  = (const float*)d_in[6];
    const float* Wl  = (const float*)d_in[7];
    const float* bl  = (const float*)d_in[8];

    const int n = in_sizes[0] / IN_DIM;   // 100000
    const int e = in_sizes[2];            // 1000000
    const int* src = ei;
    const int* dst = ei + e;

    float* out = (float*)d_out;
    const int B256 = 256;
    const int nbk = (n + BW - 1) >> BWSH;          // 391 buckets (<= 512 required)
    const int ech = (e + NCHUNK - 1) / NCHUNK;     // edges per chunk

    // workspace layout (16B-aligned slices)
    char* p = (char*)d_ws;
    int2*           sedge   = (int2*)p;            p += (size_t)e * 8;
    int2*           tmpe    = (int2*)p;            p += (size_t)e * 8;
    p = align16(p);
    float*          dinv    = (float*)p;           p += (size_t)n * 4;
    int*            offsets = (int*)p;             p += ((size_t)n + 1) * 4;
    p = align16(p);
    int*            counts  = (int*)p;             p += (size_t)NCHUNK * nbk * 4;
    int*            bstart  = (int*)p;             p += ((size_t)nbk + 1) * 4;
    p = align16(p);
    _Float16*       W1T     = (_Float16*)p;        p += IN_DIM * HID * 2;
    _Float16*       W2T     = (_Float16*)p;        p += HID * HID * 2;
    p = align16(p);
    _Float16*       A       = (_Float16*)p;        p += (size_t)n * HID * 2;
    _Float16*       B       = (_Float16*)p;        p += (size_t)n * HID * 2;

    // build: count -> scan -> bucket-partition -> fine sort (+offsets+dinv)
    k_bcount  <<<NCHUNK + 2, B256, 0, stream>>>(dst, counts, W1, W2, W1T, W2T, e, nbk, ech);
    k_bscan   <<<1, 512, 0, stream>>>(counts, bstart, offsets, n, e, nbk);
    k_bscatter<<<NCHUNK, B256, 0, stream>>>(src, dst, ew, counts, tmpe, e, nbk, ech);
    k_bfine   <<<nbk, B256, 0, stream>>>(bstart, tmpe, sedge, offsets, dinv, n);

    const int gemmBlocks = (n + 63) / 64;
    const int propBlocks = (n + 31) / 32;   // 32 nodes per 256-thread block

    k_gemm1<<<gemmBlocks, B256, 0, stream>>>(x, W1T, dinv, A, n);
    k_prop1<<<propBlocks, B256, 0, stream>>>(offsets, sedge, A, dinv, b1, B, n);

    k_gemm2<<<gemmBlocks, B256, 0, stream>>>(B, W2T, dinv, A, n);
    k_prop2_final<<<propBlocks, B256, 0, stream>>>(offsets, sedge, A, dinv,
                                                   b2, Wl, bl, out, n);
}